// Round 3
// baseline (383.561 us; speedup 1.0000x reference)
//
#include <hip/hip_runtime.h>
#include <hip/hip_bf16.h>
#include <stdint.h>

// Problem constants (reference: B,TQ,TK,D,DV = 8,2048,2048,1024,1024)
#define B_  8
#define TQ_ 2048
#define TK_ 2048
#define D_  1024
#define DV_ 1024

typedef __attribute__((ext_vector_type(8))) short  short8;
typedef __attribute__((ext_vector_type(4))) float  floatx4;

__device__ __forceinline__ void async_copy16(const void* g, void* l) {
  // 16B-per-lane global->LDS DMA. LDS dest is wave-uniform base + lane*16.
  __builtin_amdgcn_global_load_lds(
      (const __attribute__((address_space(1))) unsigned int*)g,
      (__attribute__((address_space(3))) unsigned int*)l,
      16, 0, 0);
}

__device__ __forceinline__ ushort f2bf(float f) {
  union { __hip_bfloat16 b; ushort u; } cv;
  cv.b = __float2bfloat16(f);
  return cv.u;
}

__device__ __forceinline__ float bf2f(ushort u) {
  union { ushort u; __hip_bfloat16 b; } cv;
  cv.u = u;
  return __bfloat162float(cv.b);
}

// ---------------- fused prep kernel (unchanged, verified) ----------------
__device__ __forceinline__ void transpose_body(const float* __restrict__ in,
                                               ushort* __restrict__ out,
                                               int R, int C, int r0, int c0,
                                               float (*tile)[65]) {
  const int t = threadIdx.x;
  {
    const int row = t >> 4, col = (t & 15) * 4;
    #pragma unroll
    for (int ro = 0; ro < 4; ro++) {
      const float4 f = *(const float4*)&in[(size_t)(r0 + ro * 16 + row) * C + c0 + col];
      tile[ro * 16 + row][col + 0] = f.x;
      tile[ro * 16 + row][col + 1] = f.y;
      tile[ro * 16 + row][col + 2] = f.z;
      tile[ro * 16 + row][col + 3] = f.w;
    }
  }
  __syncthreads();
  {
    const int c = t >> 4, rg = (t & 15) * 4;
    #pragma unroll
    for (int ro = 0; ro < 4; ro++) {
      const int cc = ro * 16 + c;
      ushort4 o;
      o.x = f2bf(tile[rg + 0][cc]);
      o.y = f2bf(tile[rg + 1][cc]);
      o.z = f2bf(tile[rg + 2][cc]);
      o.w = f2bf(tile[rg + 3][cc]);
      *(ushort4*)&out[(size_t)(c0 + cc) * R + r0 + rg] = o;
    }
  }
}

__global__ void prep(const float* __restrict__ q, const float* __restrict__ k,
                     const float* __restrict__ v, ushort* __restrict__ qb,
                     ushort* __restrict__ ktb, ushort* __restrict__ vtb) {
  __shared__ float tile[64][65];
  const int task = blockIdx.z >> 3;
  const int z    = blockIdx.z & 7;
  if (task == 0) {
    const float4* in  = (const float4*)(q + (size_t)z * TQ_ * D_);
    ushort4*      oup = (ushort4*)(qb + (size_t)z * TQ_ * D_);
    const int i0 = (blockIdx.y * 32 + blockIdx.x) * 1024 + threadIdx.x;
    #pragma unroll
    for (int it = 0; it < 4; it++) {
      const int i = i0 + it * 256;
      float4 f = in[i];
      ushort4 o;
      o.x = f2bf(f.x); o.y = f2bf(f.y); o.z = f2bf(f.z); o.w = f2bf(f.w);
      oup[i] = o;
    }
  } else if (task == 1) {
    transpose_body(k + (size_t)z * D_ * TK_, ktb + (size_t)z * TK_ * D_,
                   D_, TK_, blockIdx.y * 64, blockIdx.x * 64, tile);
  } else {
    transpose_body(v + (size_t)z * TK_ * DV_, vtb + (size_t)z * DV_ * TK_,
                   TK_, DV_, blockIdx.x * 64, blockIdx.y * 64, tile);
  }
}

// ---------------- 256x256-tile deep-pipeline GEMM core ----------------
// Geometry and schedule identical to round 2 (verified passing, region/FIFO
// arithmetic in comments below). ONE change: ordering is now enforced with
// __builtin_amdgcn_sched_barrier(0) (compile-time scheduling fence) instead
// of asm "memory" clobbers. The memory clobbers made the waitcnt pass treat
// every phase boundary as a potential reader of DMA-written LDS and drain
// vmcnt to 0 each phase -- reinstating the __syncthreads drain the raw
// s_barrier was supposed to avoid, and capping MfmaUtil at ~27% across all
// schedules. Bare s_barrier + bare counted s_waitcnt is the verified m201/HK
// pattern (T4): loads stay in flight across barriers.
//
// Phase = (row-half mh, k-half ks); per tile tt:
//  P1 (mh0,ks0): read a[4]+b0[4]; stage A-kh1(tt+1)           | bar | 16 MFMA | bar
//  P2 (mh1,ks0): read a[4];       stage B-kh0(tt+2); vmcnt(10)| bar | 16 MFMA | bar
//  P3 (mh0,ks1): read a[4]+b1[4]; stage A-kh0(tt+2)           | bar | 16 MFMA | bar
//  P4 (mh1,ks1): read a[4];       stage B-kh1(tt+2); vmcnt(8) | bar | 16 MFMA | bar
// Region safety: B-kh0(tt) fully read at P1 (b0 kept in regs) -> free P2;
// A-kh0(tt) read P1,P2 -> free P3; B-kh1(tt) read P3 -> free P4; A-kh1(tt+1)
// region free since tt-1 P4. Drain FIFO (2 loads/stage): vmcnt(10)@P2
// retires through tt-1 P1 (A-kh1(tt) ready for P3); vmcnt(8)@P4 retires
// through tt-1 P4 (A-kh0/B-kh0(tt+1) ready for tt+1 P1). Min issue->drain
// lead = 4 phases, max 6. Never vmcnt(0) in the loop. Tail stages wrap k
// modulo KDIM (garbage into dead regions) keeping vmcnt constants exact.
// Swizzle (verified, conflicts==0): slot s of row r holds chunk
// s ^ ((r>>1)&3); inverse pre-applied on the global source address so the
// LDS dest stays linear (global_load_lds requirement).

#define SCHED_FENCE() __builtin_amdgcn_sched_barrier(0)
#define WG_BARRIER() do { SCHED_FENCE();                        \
                          __builtin_amdgcn_s_barrier();         \
                          SCHED_FENCE(); } while (0)
#define VMCNT(n) do { asm volatile("s_waitcnt vmcnt(" #n ")");  \
                      SCHED_FENCE(); } while (0)

template <int KDIM>
__device__ __forceinline__ void gemm_core8(const ushort* __restrict__ Ap,
                                           const ushort* __restrict__ Bp,
                                           char* lds, int bm0, int bn0,
                                           floatx4 (&acc)[8][4]) {
  const int t    = threadIdx.x;
  const int lane = t & 63;
  const int w    = t >> 6;
  const int wm   = w >> 2, wn = w & 3;
  const int lc   = lane & 15, q = lane >> 4;
  const int offq = (q ^ ((lc >> 1) & 3)) * 16;   // swizzled 16B slot in 64B row
  constexpr int NT = KDIM / 64;

  // per-thread LDS read bases (row term includes wm/wn band + lc)
  const char* Abase = lds + (wm * 128 + lc) * 64 + offq;
  const char* Bbase = lds + 65536 + (wn * 64 + lc) * 64 + offq;

  // per-thread hoisted global stage bases: row = t>>2, pre-swizzled chunk
  const int srow = t >> 2;
  const int sch  = (t & 3) ^ ((t >> 3) & 3);
  const ushort* gA = Ap + (size_t)(bm0 + srow) * KDIM + sch * 8;
  const ushort* gB = Bp + (size_t)(bn0 + srow) * KDIM + sch * 8;

  auto stageA = [&](int buf, int kh, int kb) {
    char* d = lds + buf * 32768 + kh * 16384 + t * 16;
    async_copy16(gA + kb, d);
    async_copy16(gA + (size_t)128 * KDIM + kb, d + 8192);
  };
  auto stageB = [&](int buf, int kh, int kb) {
    char* d = lds + 65536 + buf * 32768 + kh * 16384 + t * 16;
    async_copy16(gB + kb, d);
    async_copy16(gB + (size_t)128 * KDIM + kb, d + 8192);
  };

  #pragma unroll
  for (int mi = 0; mi < 8; ++mi)
    #pragma unroll
    for (int ni = 0; ni < 4; ++ni)
      acc[mi][ni] = (floatx4){0.f, 0.f, 0.f, 0.f};

  // prologue: 7 halves in steady-state FIFO order, then drain the 2 oldest
  stageB(0, 0, 0);   stageA(0, 0, 0);
  stageB(0, 1, 32);  stageA(0, 1, 32);
  stageB(1, 0, 64);  stageA(1, 0, 64);
  stageB(1, 1, 96);
  VMCNT(10);
  WG_BARRIER();

  // rolling k element-offsets for the 4 stage slots (wrap keeps counts uniform)
  int kA1 = 96, kB0 = 128, kA0 = 128, kB1 = 160;

  short8 a[4], b0[4], b1[4];
  #pragma unroll 2
  for (int tt = 0; tt < NT; ++tt) {
    const int cur = tt & 1, nxt = cur ^ 1;
    const char* A  = Abase + cur * 32768;
    const char* Bq = Bbase + cur * 32768;

    // ---- P1: (mh0, ks0) ----
    #pragma unroll
    for (int j = 0; j < 4; ++j) a[j]  = *(const short8*)(A + j * 1024);
    #pragma unroll
    for (int i = 0; i < 4; ++i) b0[i] = *(const short8*)(Bq + i * 1024);
    stageA(nxt, 1, kA1); kA1 += 64; if (kA1 >= KDIM) kA1 -= KDIM;
    WG_BARRIER();
    __builtin_amdgcn_s_setprio(1);
    #pragma unroll
    for (int j = 0; j < 4; ++j)
      #pragma unroll
      for (int i = 0; i < 4; ++i)
        acc[j][i] = __builtin_amdgcn_mfma_f32_16x16x32_bf16(a[j], b0[i], acc[j][i], 0, 0, 0);
    __builtin_amdgcn_s_setprio(0);
    WG_BARRIER();

    // ---- P2: (mh1, ks0) ----
    #pragma unroll
    for (int j = 0; j < 4; ++j) a[j] = *(const short8*)(A + 4096 + j * 1024);
    stageB(cur, 0, kB0); kB0 += 64; if (kB0 >= KDIM) kB0 -= KDIM;
    VMCNT(10);
    WG_BARRIER();
    __builtin_amdgcn_s_setprio(1);
    #pragma unroll
    for (int j = 0; j < 4; ++j)
      #pragma unroll
      for (int i = 0; i < 4; ++i)
        acc[4 + j][i] = __builtin_amdgcn_mfma_f32_16x16x32_bf16(a[j], b0[i], acc[4 + j][i], 0, 0, 0);
    __builtin_amdgcn_s_setprio(0);
    WG_BARRIER();

    // ---- P3: (mh0, ks1) ----
    #pragma unroll
    for (int j = 0; j < 4; ++j) a[j]  = *(const short8*)(A + 16384 + j * 1024);
    #pragma unroll
    for (int i = 0; i < 4; ++i) b1[i] = *(const short8*)(Bq + 16384 + i * 1024);
    stageA(cur, 0, kA0); kA0 += 64; if (kA0 >= KDIM) kA0 -= KDIM;
    WG_BARRIER();
    __builtin_amdgcn_s_setprio(1);
    #pragma unroll
    for (int j = 0; j < 4; ++j)
      #pragma unroll
      for (int i = 0; i < 4; ++i)
        acc[j][i] = __builtin_amdgcn_mfma_f32_16x16x32_bf16(a[j], b1[i], acc[j][i], 0, 0, 0);
    __builtin_amdgcn_s_setprio(0);
    WG_BARRIER();

    // ---- P4: (mh1, ks1) ----
    #pragma unroll
    for (int j = 0; j < 4; ++j) a[j] = *(const short8*)(A + 16384 + 4096 + j * 1024);
    stageB(cur, 1, kB1); kB1 += 64; if (kB1 >= KDIM) kB1 -= KDIM;
    VMCNT(8);
    WG_BARRIER();
    __builtin_amdgcn_s_setprio(1);
    #pragma unroll
    for (int j = 0; j < 4; ++j)
      #pragma unroll
      for (int i = 0; i < 4; ++i)
        acc[4 + j][i] = __builtin_amdgcn_mfma_f32_16x16x32_bf16(a[j], b1[i], acc[4 + j][i], 0, 0, 0);
    __builtin_amdgcn_s_setprio(0);
    WG_BARRIER();
  }
  VMCNT(0);   // retire tail garbage DMAs before kernel end
}

// XCD-chunked bijective remap (nwg % 8 == 0): each XCD owns one contiguous
// chunk of virtual block ids -> one whole batch per XCD, so each XCD's L2
// holds only its own batch's A/B panels. (Verified: FETCH 148 -> 55.7 MB.)
__device__ __forceinline__ void xcd_coords(int& bx, int& by, int& bz) {
  const int gx = gridDim.x, gy = gridDim.y;
  int lidx = blockIdx.x + gx * (blockIdx.y + gy * blockIdx.z);
  const int nwg = gx * gy * gridDim.z;
  lidx = (lidx & 7) * (nwg >> 3) + (lidx >> 3);
  bx = lidx % gx;
  const int byz = lidx / gx;
  by = byz % gy;
  bz = byz / gy;
}

// GEMM1: P = exp(tanh(Q K + b)) in bf16; row sums of the bf16-rounded P via
// per-16-lane shuffle reduce + one atomicAdd per row-fragment.
__global__ __launch_bounds__(512, 2)
void gemm_qk(const ushort* __restrict__ Q, const ushort* __restrict__ Kt,
             const float* __restrict__ bias, ushort* __restrict__ P,
             float* __restrict__ lsum) {
  __shared__ short8 ldsv[8192];       // 128 KiB
  char* lds = (char*)ldsv;
  int bx, by, z;
  xcd_coords(bx, by, z);
  const int bm0 = by * 256;
  const int bn0 = bx * 256;

  floatx4 acc[8][4];
  gemm_core8<D_>(Q + (size_t)z * TQ_ * D_, Kt + (size_t)z * TK_ * D_,
                 lds, bm0, bn0, acc);

  const int lane = threadIdx.x & 63;
  const int w    = threadIdx.x >> 6;
  const int wm   = w >> 2, wn = w & 3;
  const int lc   = lane & 15, q = lane >> 4;
  ushort* Pb = P + (size_t)z * TQ_ * TK_;
  float*  lz = lsum + z * TQ_;

  #pragma unroll
  for (int mi = 0; mi < 8; ++mi) {
    const int grow = bm0 + wm * 128 + mi * 16 + (q << 2);
    float rs[4] = {0.f, 0.f, 0.f, 0.f};
    #pragma unroll
    for (int ni = 0; ni < 4; ++ni) {
      const int gcol = bn0 + wn * 64 + ni * 16 + lc;
      const float bj = bias[gcol];
      #pragma unroll
      for (int r = 0; r < 4; ++r) {
        float s = acc[mi][ni][r] + bj;
        // tanh(s) = 1 - 2/(e^{2s}+1); safe at +/-inf. exp(tanh) in [0.37,2.72]
        // => softmax needs no max subtraction.
        float tnh = 1.f - 2.f / (__expf(2.f * s) + 1.f);
        float p   = __expf(tnh);
        ushort pu = f2bf(p);
        Pb[(size_t)(grow + r) * TK_ + gcol] = pu;
        rs[r] += bf2f(pu);
      }
    }
    #pragma unroll
    for (int r = 0; r < 4; ++r) {
      rs[r] += __shfl_xor(rs[r], 1, 64);
      rs[r] += __shfl_xor(rs[r], 2, 64);
      rs[r] += __shfl_xor(rs[r], 4, 64);
      rs[r] += __shfl_xor(rs[r], 8, 64);
    }
    if (lc == 0) {
      #pragma unroll
      for (int r = 0; r < 4; ++r) atomicAdd(&lz[grow + r], rs[r]);
    }
  }
}

// GEMM2: out = (P Vt^T) / lsum, fp32 out
__global__ __launch_bounds__(512, 2)
void gemm_pv(const ushort* __restrict__ P, const ushort* __restrict__ Vt,
             const float* __restrict__ lsum, float* __restrict__ out) {
  __shared__ short8 ldsv[8192];       // 128 KiB
  char* lds = (char*)ldsv;
  int bx, by, z;
  xcd_coords(bx, by, z);
  const int bm0 = by * 256;
  const int bn0 = bx * 256;

  floatx4 acc[8][4];
  gemm_core8<TK_>(P + (size_t)z * TQ_ * TK_, Vt + (size_t)z * DV_ * TK_,
                  lds, bm0, bn0, acc);

  const int lane = threadIdx.x & 63;
  const int w    = threadIdx.x >> 6;
  const int wm   = w >> 2, wn = w & 3;
  const int lc   = lane & 15, q = lane >> 4;
  float* ob = out + (size_t)z * TQ_ * DV_;
  const float* lz = lsum + z * TQ_;

  #pragma unroll
  for (int mi = 0; mi < 8; ++mi) {
    const int grow = bm0 + wm * 128 + mi * 16 + (q << 2);
    float linv[4];
    #pragma unroll
    for (int r = 0; r < 4; ++r) linv[r] = 1.f / lz[grow + r];
    #pragma unroll
    for (int ni = 0; ni < 4; ++ni) {
      const int gcol = bn0 + wn * 64 + ni * 16 + lc;
      #pragma unroll
      for (int r = 0; r < 4; ++r)
        ob[(size_t)(grow + r) * DV_ + gcol] = acc[mi][ni][r] * linv[r];
    }
  }
}

// ---------------- launch ----------------
// Workspace layout (bytes):
//   qb   @ 0         : 8*2048*1024*2 = 33554432   (Q bf16)
//   ktb  @ 33554432  : 33554432                   (K^T bf16, [TK][D])
//   vtb  @ 67108864  : 33554432                   (V^T bf16, [DV][TK])
//   P    @ 100663296 : 8*2048*2048*2 = 67108864   (exp(tanh(S)) bf16)
//   lsum @ 167772160 : 8*2048*4      = 65536      (softmax denominators)
// Total: 167837696 bytes (~160 MB)

extern "C" void kernel_launch(void* const* d_in, const int* in_sizes, int n_in,
                              void* d_out, int out_size, void* d_ws, size_t ws_size,
                              hipStream_t stream) {
  const float* q    = (const float*)d_in[0];
  const float* k    = (const float*)d_in[1];
  const float* v    = (const float*)d_in[2];
  const float* bias = (const float*)d_in[3];
  float* out = (float*)d_out;

  char* ws = (char*)d_ws;
  ushort* qb   = (ushort*)(ws);
  ushort* ktb  = (ushort*)(ws + 33554432);
  ushort* vtb  = (ushort*)(ws + 67108864);
  ushort* P    = (ushort*)(ws + 100663296);
  float*  lsum = (float*)(ws + 167772160);

  hipMemsetAsync(lsum, 0, B_ * TQ_ * sizeof(float), stream);

  prep<<<dim3(32, 16, 24), dim3(256), 0, stream>>>(q, k, v, qb, ktb, vtb);

  gemm_qk<<<dim3(TK_ / 256, TQ_ / 256, B_), dim3(512), 0, stream>>>(qb, ktb, bias, P, lsum);
  gemm_pv<<<dim3(DV_ / 256, TQ_ / 256, B_), dim3(512), 0, stream>>>(P, vtb, lsum, out);
}

// Round 4
// 378.705 us; speedup vs baseline: 1.0128x; 1.0128x over previous
//
#include <hip/hip_runtime.h>
#include <hip/hip_bf16.h>
#include <stdint.h>

// Problem constants (reference: B,TQ,TK,D,DV = 8,2048,2048,1024,1024)
#define B_  8
#define TQ_ 2048
#define TK_ 2048
#define D_  1024
#define DV_ 1024

typedef __attribute__((ext_vector_type(8))) short  short8;
typedef __attribute__((ext_vector_type(4))) float  floatx4;

__device__ __forceinline__ void async_copy16(const void* g, void* l) {
  // 16B-per-lane global->LDS DMA. LDS dest is wave-uniform base + lane*16.
  __builtin_amdgcn_global_load_lds(
      (const __attribute__((address_space(1))) unsigned int*)g,
      (__attribute__((address_space(3))) unsigned int*)l,
      16, 0, 0);
}

__device__ __forceinline__ ushort f2bf(float f) {
  union { __hip_bfloat16 b; ushort u; } cv;
  cv.b = __float2bfloat16(f);
  return cv.u;
}

__device__ __forceinline__ float bf2f(ushort u) {
  union { ushort u; __hip_bfloat16 b; } cv;
  cv.u = u;
  return __bfloat162float(cv.b);
}

// ---------------- fused prep kernel (unchanged, verified) ----------------
__device__ __forceinline__ void transpose_body(const float* __restrict__ in,
                                               ushort* __restrict__ out,
                                               int R, int C, int r0, int c0,
                                               float (*tile)[65]) {
  const int t = threadIdx.x;
  {
    const int row = t >> 4, col = (t & 15) * 4;
    #pragma unroll
    for (int ro = 0; ro < 4; ro++) {
      const float4 f = *(const float4*)&in[(size_t)(r0 + ro * 16 + row) * C + c0 + col];
      tile[ro * 16 + row][col + 0] = f.x;
      tile[ro * 16 + row][col + 1] = f.y;
      tile[ro * 16 + row][col + 2] = f.z;
      tile[ro * 16 + row][col + 3] = f.w;
    }
  }
  __syncthreads();
  {
    const int c = t >> 4, rg = (t & 15) * 4;
    #pragma unroll
    for (int ro = 0; ro < 4; ro++) {
      const int cc = ro * 16 + c;
      ushort4 o;
      o.x = f2bf(tile[rg + 0][cc]);
      o.y = f2bf(tile[rg + 1][cc]);
      o.z = f2bf(tile[rg + 2][cc]);
      o.w = f2bf(tile[rg + 3][cc]);
      *(ushort4*)&out[(size_t)(c0 + cc) * R + r0 + rg] = o;
    }
  }
}

__global__ void prep(const float* __restrict__ q, const float* __restrict__ k,
                     const float* __restrict__ v, ushort* __restrict__ qb,
                     ushort* __restrict__ ktb, ushort* __restrict__ vtb) {
  __shared__ float tile[64][65];
  const int task = blockIdx.z >> 3;
  const int z    = blockIdx.z & 7;
  if (task == 0) {
    const float4* in  = (const float4*)(q + (size_t)z * TQ_ * D_);
    ushort4*      oup = (ushort4*)(qb + (size_t)z * TQ_ * D_);
    const int i0 = (blockIdx.y * 32 + blockIdx.x) * 1024 + threadIdx.x;
    #pragma unroll
    for (int it = 0; it < 4; it++) {
      const int i = i0 + it * 256;
      float4 f = in[i];
      ushort4 o;
      o.x = f2bf(f.x); o.y = f2bf(f.y); o.z = f2bf(f.z); o.w = f2bf(f.w);
      oup[i] = o;
    }
  } else if (task == 1) {
    transpose_body(k + (size_t)z * D_ * TK_, ktb + (size_t)z * TK_ * D_,
                   D_, TK_, blockIdx.y * 64, blockIdx.x * 64, tile);
  } else {
    transpose_body(v + (size_t)z * TK_ * DV_, vtb + (size_t)z * DV_ * TK_,
                   TK_, DV_, blockIdx.x * 64, blockIdx.y * 64, tile);
  }
}

// ---------------- 256x256-tile deep-pipeline GEMM core ----------------
// Geometry + schedule + FIFO/region math identical to round 2 (verified
// passing). TWO changes, both removing spurious vmcnt drains:
//  (1) Bare __builtin_amdgcn_s_barrier() and bare counted s_waitcnt asm --
//      no "memory" clobbers (round 1/2: waitcnt pass treated each fence as
//      an LDS reader -> drain), no sched_barrier(0) (round 3: m141-style
//      scheduling pessimization). This is the verified m201/HK pattern.
//  (2) LDS split into EIGHT distinct 16 KiB __shared__ arrays, one per
//      (matrix, dbuf, k-half). Alias analysis now proves each phase's
//      ds_reads touch objects with no in-flight DMA (their stages retired
//      >=4 phases earlier per the FIFO math below), so SIInsertWaitcnts
//      inserts no conservative per-phase vmcnt waits. Read-then-overwrite
//      of the same object is ordered by program order + two barriers, and
//      read completion before the next barrier is guaranteed because the
//      MFMA consuming the loaded registers executes (compiler lgkmcnt)
//      before that barrier.
//
// Phase = (row-half mh, k-half ks); per tile tt (cur = tt&1, nxt = cur^1):
//  P1 (mh0,ks0): read A[cur]K0, B[cur]K0; stage A[nxt]K1 (tt+1)   | bar | 16 MFMA | bar
//  P2 (mh1,ks0): read A[cur]K0+4K;  stage B[cur]K0 (tt+2); vmcnt(10)| bar | 16 MFMA | bar
//  P3 (mh0,ks1): read A[cur]K1, B[cur]K1; stage A[cur]K0 (tt+2)   | bar | 16 MFMA | bar
//  P4 (mh1,ks1): read A[cur]K1+4K;  stage B[cur]K1 (tt+2); vmcnt(8)| bar | 16 MFMA | bar
// FIFO retirement (2 loads/stage, verified pair-by-pair): prologue issues 7
// halves {B0K0,A0K0,B0K1,A0K1,B1K0,A1K0,B1K1}, vmcnt(10) retires the first
// two pairs (tile-0 P1 data). Steady state: vmcnt(10)@P2 retires the pairs
// needed at P3; vmcnt(8)@P4 retires the three pairs needed at tile tt+1 P1.
// Min issue->drain lead = 4 phases. Never vmcnt(0) in the loop. Tail stages
// wrap k modulo KDIM (garbage into dead regions) keeping counts uniform.
// Swizzle (verified conflict-free): slot s of row r holds chunk s^((r>>1)&3);
// inverse pre-applied on the global source (LDS dest linear, DMA requirement).

#define STG(gsrc, kb, dstarr) do {                                         \
    async_copy16((gsrc) + (kb), (char*)(dstarr) + t * 16);                 \
    async_copy16((gsrc) + g2 + (kb), (char*)(dstarr) + 8192 + t * 16);     \
  } while (0)

#define RD_A(base, extra)                                                  \
  _Pragma("unroll")                                                        \
  for (int j = 0; j < 4; ++j)                                              \
    a[j] = *(const short8*)((const char*)(base) + offA + (extra) + j * 1024);

#define RD_B(breg, base)                                                   \
  _Pragma("unroll")                                                        \
  for (int i = 0; i < 4; ++i)                                              \
    breg[i] = *(const short8*)((const char*)(base) + offB + i * 1024);

#define QMFMA(R, breg)                                                     \
  __builtin_amdgcn_s_setprio(1);                                           \
  _Pragma("unroll")                                                        \
  for (int j = 0; j < 4; ++j)                                              \
    _Pragma("unroll")                                                      \
    for (int i = 0; i < 4; ++i)                                            \
      acc[(R) + j][i] = __builtin_amdgcn_mfma_f32_16x16x32_bf16(           \
          a[j], breg[i], acc[(R) + j][i], 0, 0, 0);                        \
  __builtin_amdgcn_s_setprio(0);

#define ROLLK(kv) do { kv += 64; if (kv >= KDIM) kv -= KDIM; } while (0)

#define TILE(AK0, AK1, BK0, BK1, ANK1) do {                                \
    /* P1 (mh0, ks0) */                                                    \
    RD_A(AK0, 0); RD_B(b0, BK0);                                           \
    STG(gA, kA1, ANK1); ROLLK(kA1);                                        \
    __builtin_amdgcn_s_barrier();                                          \
    QMFMA(0, b0);                                                          \
    __builtin_amdgcn_s_barrier();                                          \
    /* P2 (mh1, ks0) */                                                    \
    RD_A(AK0, 4096);                                                       \
    STG(gB, kB0, BK0); ROLLK(kB0);                                         \
    asm volatile("s_waitcnt vmcnt(10)");                                   \
    __builtin_amdgcn_s_barrier();                                          \
    QMFMA(4, b0);                                                          \
    __builtin_amdgcn_s_barrier();                                          \
    /* P3 (mh0, ks1) */                                                    \
    RD_A(AK1, 0); RD_B(b1, BK1);                                           \
    STG(gA, kA0, AK0); ROLLK(kA0);                                         \
    __builtin_amdgcn_s_barrier();                                          \
    QMFMA(0, b1);                                                          \
    __builtin_amdgcn_s_barrier();                                          \
    /* P4 (mh1, ks1) */                                                    \
    RD_A(AK1, 4096);                                                       \
    STG(gB, kB1, BK1); ROLLK(kB1);                                         \
    asm volatile("s_waitcnt vmcnt(8)");                                    \
    __builtin_amdgcn_s_barrier();                                          \
    QMFMA(4, b1);                                                          \
    __builtin_amdgcn_s_barrier();                                          \
  } while (0)

template <int KDIM>
__device__ __forceinline__ void gemm_core8(const ushort* __restrict__ Ap,
                                           const ushort* __restrict__ Bp,
                                           int bm0, int bn0,
                                           floatx4 (&acc)[8][4]) {
  // Eight distinct LDS objects: [matrix][dbuf][k-half], 16 KiB each =
  // 256 rows x 64 B. Total 128 KiB.
  __shared__ short8 A0K0[1024], A0K1[1024], A1K0[1024], A1K1[1024];
  __shared__ short8 B0K0[1024], B0K1[1024], B1K0[1024], B1K1[1024];

  const int t    = threadIdx.x;
  const int lane = t & 63;
  const int w    = t >> 6;
  const int wm   = w >> 2, wn = w & 3;
  const int lc   = lane & 15, q = lane >> 4;
  const int offq = (q ^ ((lc >> 1) & 3)) * 16;   // swizzled 16B slot in 64B row
  const int offA = (wm * 128 + lc) * 64 + offq;
  const int offB = (wn * 64  + lc) * 64 + offq;
  constexpr int NT = KDIM / 64;

  // per-thread hoisted global stage bases: row = t>>2, pre-swizzled chunk
  const int srow = t >> 2;
  const int sch  = (t & 3) ^ ((t >> 3) & 3);
  const ushort* gA = Ap + (size_t)(bm0 + srow) * KDIM + sch * 8;
  const ushort* gB = Bp + (size_t)(bn0 + srow) * KDIM + sch * 8;
  const size_t g2 = (size_t)128 * KDIM;          // +128 rows for 2nd DMA half

  #pragma unroll
  for (int mi = 0; mi < 8; ++mi)
    #pragma unroll
    for (int ni = 0; ni < 4; ++ni)
      acc[mi][ni] = (floatx4){0.f, 0.f, 0.f, 0.f};

  // prologue: 7 halves in steady-state FIFO order, then drain the 2 oldest
  STG(gB, 0,  B0K0);  STG(gA, 0,  A0K0);
  STG(gB, 32, B0K1);  STG(gA, 32, A0K1);
  STG(gB, 64, B1K0);  STG(gA, 64, A1K0);
  STG(gB, 96, B1K1);
  asm volatile("s_waitcnt vmcnt(10)");
  __builtin_amdgcn_s_barrier();

  // rolling k element-offsets for the 4 stage slots (wrap keeps counts uniform)
  int kA1 = 96, kB0 = 128, kA0 = 128, kB1 = 160;

  short8 a[4], b0[4], b1[4];
  for (int t2 = 0; t2 < NT / 2; ++t2) {
    TILE(A0K0, A0K1, B0K0, B0K1, A1K1);   // tt even: cur=0, stages A1K1
    TILE(A1K0, A1K1, B1K0, B1K1, A0K1);   // tt odd : cur=1, stages A0K1
  }
  asm volatile("s_waitcnt vmcnt(0)");     // retire tail garbage DMAs
}

// XCD-chunked bijective remap (nwg % 8 == 0): each XCD owns one contiguous
// chunk of virtual block ids -> one whole batch per XCD, so each XCD's L2
// holds only its own batch's A/B panels. (Verified: FETCH 148 -> 55.7 MB.)
__device__ __forceinline__ void xcd_coords(int& bx, int& by, int& bz) {
  const int gx = gridDim.x, gy = gridDim.y;
  int lidx = blockIdx.x + gx * (blockIdx.y + gy * blockIdx.z);
  const int nwg = gx * gy * gridDim.z;
  lidx = (lidx & 7) * (nwg >> 3) + (lidx >> 3);
  bx = lidx % gx;
  const int byz = lidx / gx;
  by = byz % gy;
  bz = byz / gy;
}

// GEMM1: P = exp(tanh(Q K + b)) in bf16; row sums of the bf16-rounded P via
// per-16-lane shuffle reduce + one atomicAdd per row-fragment.
__global__ __launch_bounds__(512, 2)
void gemm_qk(const ushort* __restrict__ Q, const ushort* __restrict__ Kt,
             const float* __restrict__ bias, ushort* __restrict__ P,
             float* __restrict__ lsum) {
  int bx, by, z;
  xcd_coords(bx, by, z);
  const int bm0 = by * 256;
  const int bn0 = bx * 256;

  floatx4 acc[8][4];
  gemm_core8<D_>(Q + (size_t)z * TQ_ * D_, Kt + (size_t)z * TK_ * D_,
                 bm0, bn0, acc);

  const int lane = threadIdx.x & 63;
  const int w    = threadIdx.x >> 6;
  const int wm   = w >> 2, wn = w & 3;
  const int lc   = lane & 15, q = lane >> 4;
  ushort* Pb = P + (size_t)z * TQ_ * TK_;
  float*  lz = lsum + z * TQ_;

  #pragma unroll
  for (int mi = 0; mi < 8; ++mi) {
    const int grow = bm0 + wm * 128 + mi * 16 + (q << 2);
    float rs[4] = {0.f, 0.f, 0.f, 0.f};
    #pragma unroll
    for (int ni = 0; ni < 4; ++ni) {
      const int gcol = bn0 + wn * 64 + ni * 16 + lc;
      const float bj = bias[gcol];
      #pragma unroll
      for (int r = 0; r < 4; ++r) {
        float s = acc[mi][ni][r] + bj;
        // tanh(s) = 1 - 2/(e^{2s}+1); safe at +/-inf. exp(tanh) in [0.37,2.72]
        // => softmax needs no max subtraction.
        float tnh = 1.f - 2.f / (__expf(2.f * s) + 1.f);
        float p   = __expf(tnh);
        ushort pu = f2bf(p);
        Pb[(size_t)(grow + r) * TK_ + gcol] = pu;
        rs[r] += bf2f(pu);
      }
    }
    #pragma unroll
    for (int r = 0; r < 4; ++r) {
      rs[r] += __shfl_xor(rs[r], 1, 64);
      rs[r] += __shfl_xor(rs[r], 2, 64);
      rs[r] += __shfl_xor(rs[r], 4, 64);
      rs[r] += __shfl_xor(rs[r], 8, 64);
    }
    if (lc == 0) {
      #pragma unroll
      for (int r = 0; r < 4; ++r) atomicAdd(&lz[grow + r], rs[r]);
    }
  }
}

// GEMM2: out = (P Vt^T) / lsum, fp32 out
__global__ __launch_bounds__(512, 2)
void gemm_pv(const ushort* __restrict__ P, const ushort* __restrict__ Vt,
             const float* __restrict__ lsum, float* __restrict__ out) {
  int bx, by, z;
  xcd_coords(bx, by, z);
  const int bm0 = by * 256;
  const int bn0 = bx * 256;

  floatx4 acc[8][4];
  gemm_core8<TK_>(P + (size_t)z * TQ_ * TK_, Vt + (size_t)z * DV_ * TK_,
                  bm0, bn0, acc);

  const int lane = threadIdx.x & 63;
  const int w    = threadIdx.x >> 6;
  const int wm   = w >> 2, wn = w & 3;
  const int lc   = lane & 15, q = lane >> 4;
  float* ob = out + (size_t)z * TQ_ * DV_;
  const float* lz = lsum + z * TQ_;

  #pragma unroll
  for (int mi = 0; mi < 8; ++mi) {
    const int grow = bm0 + wm * 128 + mi * 16 + (q << 2);
    float linv[4];
    #pragma unroll
    for (int r = 0; r < 4; ++r) linv[r] = 1.f / lz[grow + r];
    #pragma unroll
    for (int ni = 0; ni < 4; ++ni) {
      const int gcol = bn0 + wn * 64 + ni * 16 + lc;
      #pragma unroll
      for (int r = 0; r < 4; ++r)
        ob[(size_t)(grow + r) * DV_ + gcol] = acc[mi][ni][r] * linv[r];
    }
  }
}

// ---------------- launch ----------------
// Workspace layout (bytes):
//   qb   @ 0         : 8*2048*1024*2 = 33554432   (Q bf16)
//   ktb  @ 33554432  : 33554432                   (K^T bf16, [TK][D])
//   vtb  @ 67108864  : 33554432                   (V^T bf16, [DV][TK])
//   P    @ 100663296 : 8*2048*2048*2 = 67108864   (exp(tanh(S)) bf16)
//   lsum @ 167772160 : 8*2048*4      = 65536      (softmax denominators)
// Total: 167837696 bytes (~160 MB)

extern "C" void kernel_launch(void* const* d_in, const int* in_sizes, int n_in,
                              void* d_out, int out_size, void* d_ws, size_t ws_size,
                              hipStream_t stream) {
  const float* q    = (const float*)d_in[0];
  const float* k    = (const float*)d_in[1];
  const float* v    = (const float*)d_in[2];
  const float* bias = (const float*)d_in[3];
  float* out = (float*)d_out;

  char* ws = (char*)d_ws;
  ushort* qb   = (ushort*)(ws);
  ushort* ktb  = (ushort*)(ws + 33554432);
  ushort* vtb  = (ushort*)(ws + 67108864);
  ushort* P    = (ushort*)(ws + 100663296);
  float*  lsum = (float*)(ws + 167772160);

  hipMemsetAsync(lsum, 0, B_ * TQ_ * sizeof(float), stream);

  prep<<<dim3(32, 16, 24), dim3(256), 0, stream>>>(q, k, v, qb, ktb, vtb);

  gemm_qk<<<dim3(TK_ / 256, TQ_ / 256, B_), dim3(512), 0, stream>>>(qb, ktb, bias, P, lsum);
  gemm_pv<<<dim3(DV_ / 256, TQ_ / 256, B_), dim3(512), 0, stream>>>(P, vtb, lsum, out);
}

// Round 5
// 376.865 us; speedup vs baseline: 1.0178x; 1.0049x over previous
//
#include <hip/hip_runtime.h>
#include <hip/hip_bf16.h>
#include <stdint.h>

// Problem constants (reference: B,TQ,TK,D,DV = 8,2048,2048,1024,1024)
#define B_  8
#define TQ_ 2048
#define TK_ 2048
#define D_  1024
#define DV_ 1024

typedef __attribute__((ext_vector_type(8))) short  short8;
typedef __attribute__((ext_vector_type(4))) float  floatx4;

__device__ __forceinline__ void async_copy16(const void* g, void* l) {
  // 16B-per-lane global->LDS DMA. LDS dest is wave-uniform base + lane*16.
  __builtin_amdgcn_global_load_lds(
      (const __attribute__((address_space(1))) unsigned int*)g,
      (__attribute__((address_space(3))) unsigned int*)l,
      16, 0, 0);
}

__device__ __forceinline__ ushort f2bf(float f) {
  union { __hip_bfloat16 b; ushort u; } cv;
  cv.b = __float2bfloat16(f);
  return cv.u;
}

__device__ __forceinline__ float bf2f(ushort u) {
  union { ushort u; __hip_bfloat16 b; } cv;
  cv.u = u;
  return __bfloat162float(cv.b);
}

// ---------------- fused prep kernel (unchanged, verified) ----------------
__device__ __forceinline__ void transpose_body(const float* __restrict__ in,
                                               ushort* __restrict__ out,
                                               int R, int C, int r0, int c0,
                                               float (*tile)[65]) {
  const int t = threadIdx.x;
  {
    const int row = t >> 4, col = (t & 15) * 4;
    #pragma unroll
    for (int ro = 0; ro < 4; ro++) {
      const float4 f = *(const float4*)&in[(size_t)(r0 + ro * 16 + row) * C + c0 + col];
      tile[ro * 16 + row][col + 0] = f.x;
      tile[ro * 16 + row][col + 1] = f.y;
      tile[ro * 16 + row][col + 2] = f.z;
      tile[ro * 16 + row][col + 3] = f.w;
    }
  }
  __syncthreads();
  {
    const int c = t >> 4, rg = (t & 15) * 4;
    #pragma unroll
    for (int ro = 0; ro < 4; ro++) {
      const int cc = ro * 16 + c;
      ushort4 o;
      o.x = f2bf(tile[rg + 0][cc]);
      o.y = f2bf(tile[rg + 1][cc]);
      o.z = f2bf(tile[rg + 2][cc]);
      o.w = f2bf(tile[rg + 3][cc]);
      *(ushort4*)&out[(size_t)(c0 + cc) * R + r0 + rg] = o;
    }
  }
}

__global__ void prep(const float* __restrict__ q, const float* __restrict__ k,
                     const float* __restrict__ v, ushort* __restrict__ qb,
                     ushort* __restrict__ ktb, ushort* __restrict__ vtb) {
  __shared__ float tile[64][65];
  const int task = blockIdx.z >> 3;
  const int z    = blockIdx.z & 7;
  if (task == 0) {
    const float4* in  = (const float4*)(q + (size_t)z * TQ_ * D_);
    ushort4*      oup = (ushort4*)(qb + (size_t)z * TQ_ * D_);
    const int i0 = (blockIdx.y * 32 + blockIdx.x) * 1024 + threadIdx.x;
    #pragma unroll
    for (int it = 0; it < 4; it++) {
      const int i = i0 + it * 256;
      float4 f = in[i];
      ushort4 o;
      o.x = f2bf(f.x); o.y = f2bf(f.y); o.z = f2bf(f.z); o.w = f2bf(f.w);
      oup[i] = o;
    }
  } else if (task == 1) {
    transpose_body(k + (size_t)z * D_ * TK_, ktb + (size_t)z * TK_ * D_,
                   D_, TK_, blockIdx.y * 64, blockIdx.x * 64, tile);
  } else {
    transpose_body(v + (size_t)z * TK_ * DV_, vtb + (size_t)z * DV_ * TK_,
                   TK_, DV_, blockIdx.x * 64, blockIdx.y * 64, tile);
  }
}

// ================= QK core: R2 verbatim (profiled anchor, 107us) =========
// 256x256, BK=64 split in k-halves, clobbered barriers, vmcnt(10/8).
// Kept byte-identical to round 2 as the control arm.

#define WGB_Q() do { asm volatile("" ::: "memory");        \
                     __builtin_amdgcn_s_barrier();         \
                     asm volatile("" ::: "memory"); } while (0)
#define VMC_Q(n) asm volatile("s_waitcnt vmcnt(" #n ")" ::: "memory")

template <int KDIM>
__device__ __forceinline__ void gemm_core_qk(const ushort* __restrict__ Ap,
                                             const ushort* __restrict__ Bp,
                                             char* lds, int bm0, int bn0,
                                             floatx4 (&acc)[8][4]) {
  const int t    = threadIdx.x;
  const int lane = t & 63;
  const int w    = t >> 6;
  const int wm   = w >> 2, wn = w & 3;
  const int lc   = lane & 15, q = lane >> 4;
  const int offq = (q ^ ((lc >> 1) & 3)) * 16;   // swizzled 16B slot in 64B row
  constexpr int NT = KDIM / 64;

  const char* Abase = lds + (wm * 128 + lc) * 64 + offq;
  const char* Bbase = lds + 65536 + (wn * 64 + lc) * 64 + offq;

  const int srow = t >> 2;
  const int sch  = (t & 3) ^ ((t >> 3) & 3);
  const ushort* gA = Ap + (size_t)(bm0 + srow) * KDIM + sch * 8;
  const ushort* gB = Bp + (size_t)(bn0 + srow) * KDIM + sch * 8;

  auto stageA = [&](int buf, int kh, int kb) {
    char* d = lds + buf * 32768 + kh * 16384 + t * 16;
    async_copy16(gA + kb, d);
    async_copy16(gA + (size_t)128 * KDIM + kb, d + 8192);
  };
  auto stageB = [&](int buf, int kh, int kb) {
    char* d = lds + 65536 + buf * 32768 + kh * 16384 + t * 16;
    async_copy16(gB + kb, d);
    async_copy16(gB + (size_t)128 * KDIM + kb, d + 8192);
  };

  #pragma unroll
  for (int mi = 0; mi < 8; ++mi)
    #pragma unroll
    for (int ni = 0; ni < 4; ++ni)
      acc[mi][ni] = (floatx4){0.f, 0.f, 0.f, 0.f};

  // prologue: 7 halves in steady-state FIFO order, then drain the 2 oldest
  stageB(0, 0, 0);   stageA(0, 0, 0);
  stageB(0, 1, 32);  stageA(0, 1, 32);
  stageB(1, 0, 64);  stageA(1, 0, 64);
  stageB(1, 1, 96);
  VMC_Q(10);
  WGB_Q();

  int kA1 = 96, kB0 = 128, kA0 = 128, kB1 = 160;

  short8 a[4], b0[4], b1[4];
  #pragma unroll 2
  for (int tt = 0; tt < NT; ++tt) {
    const int cur = tt & 1, nxt = cur ^ 1;
    const char* A  = Abase + cur * 32768;
    const char* Bq = Bbase + cur * 32768;

    // ---- P1: (mh0, ks0) ----
    #pragma unroll
    for (int j = 0; j < 4; ++j) a[j]  = *(const short8*)(A + j * 1024);
    #pragma unroll
    for (int i = 0; i < 4; ++i) b0[i] = *(const short8*)(Bq + i * 1024);
    stageA(nxt, 1, kA1); kA1 += 64; if (kA1 >= KDIM) kA1 -= KDIM;
    WGB_Q();
    __builtin_amdgcn_s_setprio(1);
    #pragma unroll
    for (int j = 0; j < 4; ++j)
      #pragma unroll
      for (int i = 0; i < 4; ++i)
        acc[j][i] = __builtin_amdgcn_mfma_f32_16x16x32_bf16(a[j], b0[i], acc[j][i], 0, 0, 0);
    __builtin_amdgcn_s_setprio(0);
    WGB_Q();

    // ---- P2: (mh1, ks0) ----
    #pragma unroll
    for (int j = 0; j < 4; ++j) a[j] = *(const short8*)(A + 4096 + j * 1024);
    stageB(cur, 0, kB0); kB0 += 64; if (kB0 >= KDIM) kB0 -= KDIM;
    VMC_Q(10);
    WGB_Q();
    __builtin_amdgcn_s_setprio(1);
    #pragma unroll
    for (int j = 0; j < 4; ++j)
      #pragma unroll
      for (int i = 0; i < 4; ++i)
        acc[4 + j][i] = __builtin_amdgcn_mfma_f32_16x16x32_bf16(a[j], b0[i], acc[4 + j][i], 0, 0, 0);
    __builtin_amdgcn_s_setprio(0);
    WGB_Q();

    // ---- P3: (mh0, ks1) ----
    #pragma unroll
    for (int j = 0; j < 4; ++j) a[j]  = *(const short8*)(A + 16384 + j * 1024);
    #pragma unroll
    for (int i = 0; i < 4; ++i) b1[i] = *(const short8*)(Bq + 16384 + i * 1024);
    stageA(cur, 0, kA0); kA0 += 64; if (kA0 >= KDIM) kA0 -= KDIM;
    WGB_Q();
    __builtin_amdgcn_s_setprio(1);
    #pragma unroll
    for (int j = 0; j < 4; ++j)
      #pragma unroll
      for (int i = 0; i < 4; ++i)
        acc[j][i] = __builtin_amdgcn_mfma_f32_16x16x32_bf16(a[j], b1[i], acc[j][i], 0, 0, 0);
    __builtin_amdgcn_s_setprio(0);
    WGB_Q();

    // ---- P4: (mh1, ks1) ----
    #pragma unroll
    for (int j = 0; j < 4; ++j) a[j] = *(const short8*)(A + 16384 + 4096 + j * 1024);
    stageB(cur, 1, kB1); kB1 += 64; if (kB1 >= KDIM) kB1 -= KDIM;
    VMC_Q(8);
    WGB_Q();
    __builtin_amdgcn_s_setprio(1);
    #pragma unroll
    for (int j = 0; j < 4; ++j)
      #pragma unroll
      for (int i = 0; i < 4; ++i)
        acc[4 + j][i] = __builtin_amdgcn_mfma_f32_16x16x32_bf16(a[j], b1[i], acc[4 + j][i], 0, 0, 0);
    __builtin_amdgcn_s_setprio(0);
    WGB_Q();
  }
  VMC_Q(0);
}

// ================= PV core: v5 pipelined single-barrier ==================
// Same geometry (256x256, BK=64 k-halves, 8 split 16KB LDS arrays, same
// verified swizzle pair). NEW schedule: ONE barrier per phase; each phase =
//   bar | [counted vmcnt] | stage-issue | 16 MFMA (regs read LAST phase) |
//   ds_read next phase's fragments (execute in other waves' MFMA shadow)
// Register ping-pong: aX used P1/P3, aY used P2/P4; b0 used P1/P2 (read in
// prior P4), b1 used P3/P4 (read in P2). All indices static (rule #20).
// Motion pinning: sched_barrier(0xF) on both sides of each s_barrier --
// DS/VMEM may not cross phase boundaries, VALU/SALU/MFMA may (avoids R3's
// sched_barrier(0) pessimization).
// FIFO drains (2 loads/stage-call, vmcnt BEFORE the phase's stage):
//   P2-start vmcnt(8): queue [A(tt)K1, B(tt+1)K0, A(tt+1)K0, B(tt+1)K1,
//     A(tt+1)K1] = 10 -> retires A(tt)K1 pair, exactly what P2-end reads
//     (aX<-A(tt)K1 mh0, b1<-B(tt)K1: B(tt)K1 retired at P4(tt-1)).
//   P4-start vmcnt(6): queue 10 -> retires through A(tt+1)K0 pair + its
//     predecessors (B(tt+1)K0), covering P4-end reads (aX<-A(tt+1)K0 mh0,
//     b0<-B(tt+1)K0). Issue->drain lead 5 phases. Never vmcnt(0) in loop.
// Overwrite safety (>=1 barrier between last read and DMA-issue):
//   A[cur]K0 staged P3, last read P1-end (2 bars); A[nxt]K1 staged P1, last
//   read P3(tt-1)-end (2 bars); B[cur]K0 staged P2, last read P4(tt-1)-end
//   (2 bars); B[cur]K1 staged P4, last read P2-end (2 bars).
// Tail reads fetch wrapped garbage into dead regs (unused); final vmcnt(0).

#define SB_F() __builtin_amdgcn_sched_barrier(0xF)
#define PV_BAR() do { SB_F(); __builtin_amdgcn_s_barrier(); SB_F(); } while (0)

#define STG(gsrc, kb, dstarr) do {                                         \
    async_copy16((gsrc) + (kb), (char*)(dstarr) + t * 16);                 \
    async_copy16((gsrc) + g2 + (kb), (char*)(dstarr) + 8192 + t * 16);     \
  } while (0)

#define RD4(dst, arr, extra)                                               \
  _Pragma("unroll")                                                        \
  for (int j = 0; j < 4; ++j)                                              \
    dst[j] = *(const short8*)((const char*)(arr) + offA + (extra) + j * 1024);

#define RDB(dst, arr)                                                      \
  _Pragma("unroll")                                                        \
  for (int i = 0; i < 4; ++i)                                              \
    dst[i] = *(const short8*)((const char*)(arr) + offB + i * 1024);

#define MM8(R, aset, bset)                                                 \
  __builtin_amdgcn_s_setprio(1);                                           \
  _Pragma("unroll")                                                        \
  for (int j = 0; j < 4; ++j)                                              \
    _Pragma("unroll")                                                      \
    for (int i = 0; i < 4; ++i)                                            \
      acc[(R) + j][i] = __builtin_amdgcn_mfma_f32_16x16x32_bf16(           \
          aset[j], bset[i], acc[(R) + j][i], 0, 0, 0);                     \
  __builtin_amdgcn_s_setprio(0);

#define ROLLK(kv) do { kv += 64; if (kv >= KDIM) kv -= KDIM; } while (0)

#define PV_TILE(AK0, AK1, BK0, BK1, ANK0, ANK1, BNK0) do {                 \
    /* P1: MFMA(aX,b0); stage A[nxt]K1; read aY<-AK0 mh1 */                \
    PV_BAR();                                                              \
    STG(gA, kA1, ANK1); ROLLK(kA1);                                        \
    MM8(0, aX, b0);                                                        \
    RD4(aY, AK0, 4096);                                                    \
    /* P2: vmcnt(8); stage B[cur]K0; MFMA(aY,b0); read aX<-AK1, b1<-BK1 */ \
    PV_BAR();                                                              \
    asm volatile("s_waitcnt vmcnt(8)");                                    \
    STG(gB, kB0, BK0); ROLLK(kB0);                                         \
    MM8(4, aY, b0);                                                        \
    RD4(aX, AK1, 0);                                                       \
    RDB(b1, BK1);                                                          \
    /* P3: stage A[cur]K0; MFMA(aX,b1); read aY<-AK1 mh1 */                \
    PV_BAR();                                                              \
    STG(gA, kA0, AK0); ROLLK(kA0);                                         \
    MM8(0, aX, b1);                                                        \
    RD4(aY, AK1, 4096);                                                    \
    /* P4: vmcnt(6); stage B[cur]K1; MFMA(aY,b1); read aX<-ANK0, b0<-BNK0 */\
    PV_BAR();                                                              \
    asm volatile("s_waitcnt vmcnt(6)");                                    \
    STG(gB, kB1, BK1); ROLLK(kB1);                                         \
    MM8(4, aY, b1);                                                        \
    RD4(aX, ANK0, 0);                                                      \
    RDB(b0, BNK0);                                                         \
  } while (0)

template <int KDIM>
__device__ __forceinline__ void gemm_core_pv(const ushort* __restrict__ Ap,
                                             const ushort* __restrict__ Bp,
                                             int bm0, int bn0,
                                             floatx4 (&acc)[8][4]) {
  __shared__ short8 A0K0[1024], A0K1[1024], A1K0[1024], A1K1[1024];
  __shared__ short8 B0K0[1024], B0K1[1024], B1K0[1024], B1K1[1024];

  const int t    = threadIdx.x;
  const int lane = t & 63;
  const int w    = t >> 6;
  const int wm   = w >> 2, wn = w & 3;
  const int lc   = lane & 15, q = lane >> 4;
  const int offq = (q ^ ((lc >> 1) & 3)) * 16;
  const int offA = (wm * 128 + lc) * 64 + offq;
  const int offB = (wn * 64  + lc) * 64 + offq;
  constexpr int NT = KDIM / 64;

  const int srow = t >> 2;
  const int sch  = (t & 3) ^ ((t >> 3) & 3);
  const ushort* gA = Ap + (size_t)(bm0 + srow) * KDIM + sch * 8;
  const ushort* gB = Bp + (size_t)(bn0 + srow) * KDIM + sch * 8;
  const size_t g2 = (size_t)128 * KDIM;

  #pragma unroll
  for (int mi = 0; mi < 8; ++mi)
    #pragma unroll
    for (int ni = 0; ni < 4; ++ni)
      acc[mi][ni] = (floatx4){0.f, 0.f, 0.f, 0.f};

  // prologue: 7 halves FIFO, drain 2 oldest, pre-read P1 fragments
  STG(gB, 0,  B0K0);  STG(gA, 0,  A0K0);
  STG(gB, 32, B0K1);  STG(gA, 32, A0K1);
  STG(gB, 64, B1K0);  STG(gA, 64, A1K0);
  STG(gB, 96, B1K1);
  asm volatile("s_waitcnt vmcnt(10)");
  __builtin_amdgcn_s_barrier();
  SB_F();

  short8 aX[4], aY[4], b0[4], b1[4];
  RD4(aX, A0K0, 0);
  RDB(b0, B0K0);

  int kA1 = 96, kB0 = 128, kA0 = 128, kB1 = 160;

  for (int t2 = 0; t2 < NT / 2; ++t2) {
    PV_TILE(A0K0, A0K1, B0K0, B0K1, A1K0, A1K1, B1K0);  // cur=0
    PV_TILE(A1K0, A1K1, B1K0, B1K1, A0K0, A0K1, B0K0);  // cur=1
  }
  asm volatile("s_waitcnt vmcnt(0)");   // retire tail garbage DMAs
}

// XCD-chunked bijective remap (nwg % 8 == 0): one batch per XCD.
// (Verified: FETCH 148 -> 55.7 MB.)
__device__ __forceinline__ void xcd_coords(int& bx, int& by, int& bz) {
  const int gx = gridDim.x, gy = gridDim.y;
  int lidx = blockIdx.x + gx * (blockIdx.y + gy * blockIdx.z);
  const int nwg = gx * gy * gridDim.z;
  lidx = (lidx & 7) * (nwg >> 3) + (lidx >> 3);
  bx = lidx % gx;
  const int byz = lidx / gx;
  by = byz % gy;
  bz = byz / gy;
}

// GEMM1: P = exp(tanh(Q K + b)) in bf16; row sums via shuffle + atomicAdd.
__global__ __launch_bounds__(512, 2)
void gemm_qk(const ushort* __restrict__ Q, const ushort* __restrict__ Kt,
             const float* __restrict__ bias, ushort* __restrict__ P,
             float* __restrict__ lsum) {
  __shared__ short8 ldsv[8192];       // 128 KiB
  char* lds = (char*)ldsv;
  int bx, by, z;
  xcd_coords(bx, by, z);
  const int bm0 = by * 256;
  const int bn0 = bx * 256;

  floatx4 acc[8][4];
  gemm_core_qk<D_>(Q + (size_t)z * TQ_ * D_, Kt + (size_t)z * TK_ * D_,
                   lds, bm0, bn0, acc);

  const int lane = threadIdx.x & 63;
  const int w    = threadIdx.x >> 6;
  const int wm   = w >> 2, wn = w & 3;
  const int lc   = lane & 15, q = lane >> 4;
  ushort* Pb = P + (size_t)z * TQ_ * TK_;
  float*  lz = lsum + z * TQ_;

  #pragma unroll
  for (int mi = 0; mi < 8; ++mi) {
    const int grow = bm0 + wm * 128 + mi * 16 + (q << 2);
    float rs[4] = {0.f, 0.f, 0.f, 0.f};
    #pragma unroll
    for (int ni = 0; ni < 4; ++ni) {
      const int gcol = bn0 + wn * 64 + ni * 16 + lc;
      const float bj = bias[gcol];
      #pragma unroll
      for (int r = 0; r < 4; ++r) {
        float s = acc[mi][ni][r] + bj;
        // tanh(s) = 1 - 2/(e^{2s}+1); safe at +/-inf. exp(tanh) in [0.37,2.72]
        // => softmax needs no max subtraction.
        float tnh = 1.f - 2.f / (__expf(2.f * s) + 1.f);
        float p   = __expf(tnh);
        ushort pu = f2bf(p);
        Pb[(size_t)(grow + r) * TK_ + gcol] = pu;
        rs[r] += bf2f(pu);
      }
    }
    #pragma unroll
    for (int r = 0; r < 4; ++r) {
      rs[r] += __shfl_xor(rs[r], 1, 64);
      rs[r] += __shfl_xor(rs[r], 2, 64);
      rs[r] += __shfl_xor(rs[r], 4, 64);
      rs[r] += __shfl_xor(rs[r], 8, 64);
    }
    if (lc == 0) {
      #pragma unroll
      for (int r = 0; r < 4; ++r) atomicAdd(&lz[grow + r], rs[r]);
    }
  }
}

// GEMM2: out = (P Vt^T) / lsum, fp32 out — v5 pipelined core
__global__ __launch_bounds__(512, 2)
void gemm_pv(const ushort* __restrict__ P, const ushort* __restrict__ Vt,
             const float* __restrict__ lsum, float* __restrict__ out) {
  int bx, by, z;
  xcd_coords(bx, by, z);
  const int bm0 = by * 256;
  const int bn0 = bx * 256;

  floatx4 acc[8][4];
  gemm_core_pv<TK_>(P + (size_t)z * TQ_ * TK_, Vt + (size_t)z * DV_ * TK_,
                    bm0, bn0, acc);

  const int lane = threadIdx.x & 63;
  const int w    = threadIdx.x >> 6;
  const int wm   = w >> 2, wn = w & 3;
  const int lc   = lane & 15, q = lane >> 4;
  float* ob = out + (size_t)z * TQ_ * DV_;
  const float* lz = lsum + z * TQ_;

  #pragma unroll
  for (int mi = 0; mi < 8; ++mi) {
    const int grow = bm0 + wm * 128 + mi * 16 + (q << 2);
    float linv[4];
    #pragma unroll
    for (int r = 0; r < 4; ++r) linv[r] = 1.f / lz[grow + r];
    #pragma unroll
    for (int ni = 0; ni < 4; ++ni) {
      const int gcol = bn0 + wn * 64 + ni * 16 + lc;
      #pragma unroll
      for (int r = 0; r < 4; ++r)
        ob[(size_t)(grow + r) * DV_ + gcol] = acc[mi][ni][r] * linv[r];
    }
  }
}

// ---------------- launch ----------------
// Workspace layout (bytes):
//   qb   @ 0         : 8*2048*1024*2 = 33554432   (Q bf16)
//   ktb  @ 33554432  : 33554432                   (K^T bf16, [TK][D])
//   vtb  @ 67108864  : 33554432                   (V^T bf16, [DV][TK])
//   P    @ 100663296 : 8*2048*2048*2 = 67108864   (exp(tanh(S)) bf16)
//   lsum @ 167772160 : 8*2048*4      = 65536      (softmax denominators)
// Total: 167837696 bytes (~160 MB)

extern "C" void kernel_launch(void* const* d_in, const int* in_sizes, int n_in,
                              void* d_out, int out_size, void* d_ws, size_t ws_size,
                              hipStream_t stream) {
  const float* q    = (const float*)d_in[0];
  const float* k    = (const float*)d_in[1];
  const float* v    = (const float*)d_in[2];
  const float* bias = (const float*)d_in[3];
  float* out = (float*)d_out;

  char* ws = (char*)d_ws;
  ushort* qb   = (ushort*)(ws);
  ushort* ktb  = (ushort*)(ws + 33554432);
  ushort* vtb  = (ushort*)(ws + 67108864);
  ushort* P    = (ushort*)(ws + 100663296);
  float*  lsum = (float*)(ws + 167772160);

  hipMemsetAsync(lsum, 0, B_ * TQ_ * sizeof(float), stream);

  prep<<<dim3(32, 16, 24), dim3(256), 0, stream>>>(q, k, v, qb, ktb, vtb);

  gemm_qk<<<dim3(TK_ / 256, TQ_ / 256, B_), dim3(512), 0, stream>>>(qb, ktb, bias, P, lsum);
  gemm_pv<<<dim3(DV_ / 256, TQ_ / 256, B_), dim3(512), 0, stream>>>(P, vtb, lsum, out);
}